// Round 1
// baseline (291.848 us; speedup 1.0000x reference)
//
#include <hip/hip_runtime.h>

#define EPS 1e-12f

typedef float vf4 __attribute__((ext_vector_type(4)));
typedef int   vi2 __attribute__((ext_vector_type(2)));

__device__ __forceinline__ float sel8(const vf4& a, const vf4& b, int i) {
    float lo = (i == 0) ? a.x : (i == 1) ? a.y : (i == 2) ? a.z : a.w;
    float hi = (i == 4) ? b.x : (i == 5) ? b.y : (i == 6) ? b.z : b.w;
    return (i < 4) ? lo : hi;
}

__device__ __forceinline__ float sel4(const vf4& q, int i) {
    return (i == 0) ? q.x : (i == 1) ? q.y : (i == 2) ? q.z : q.w;
}

// Single direct kernel: NO workspace, NO repack pass.
// Gathers dims + t-row + c-row concurrently (no dims->table serialization),
// then the two aligned value quads. 3-level memory chain per eval.
__global__ __launch_bounds__(256) void TimingPropagation_35622458753425_kernel(
    const float* __restrict__ x_t_arr, const float* __restrict__ x_c_arr,
    const int* __restrict__ arcs, const float* __restrict__ values,
    const float* __restrict__ t_table, const float* __restrict__ c_table,
    const int* __restrict__ dims, float* __restrict__ out, int B)
{
    int i = blockIdx.x * blockDim.x + threadIdx.x;
    if (i >= B) return;
    float x_t = __builtin_nontemporal_load(x_t_arr + i);
    float x_c = __builtin_nontemporal_load(x_c_arr + i);
    int arc = __builtin_nontemporal_load(arcs + i);

    // Issue all three per-arc gathers back-to-back; dims first so the
    // compiler can wait on it with the 4 table loads still in flight.
    vi2 d = *(const vi2*)(dims + (size_t)2 * arc);
    const vf4* tt = (const vf4*)(t_table + (size_t)arc * 8);
    const vf4* cc = (const vf4*)(c_table + (size_t)arc * 8);
    vf4 ta = tt[0];
    vf4 tb = tt[1];
    vf4 ca = cc[0];
    vf4 cb = cc[1];

    int td = d.x, cd = d.y;
    // invalid arcs (~21%): store 0, skip the value-row gathers
    if (td == 0 || cd == 0) { __builtin_nontemporal_store(0.0f, out + i); return; }

    // branchless searchsorted(side='right') over the 8 breakpoints
    int ss_t = (ta.x <= x_t) + (ta.y <= x_t) + (ta.z <= x_t) + (ta.w <= x_t)
             + (tb.x <= x_t) + (tb.y <= x_t) + (tb.z <= x_t) + (tb.w <= x_t);
    int ss_c = (ca.x <= x_c) + (ca.y <= x_c) + (ca.z <= x_c) + (ca.w <= x_c)
             + (cb.x <= x_c) + (cb.y <= x_c) + (cb.z <= x_c) + (cb.w <= x_c);

    int t_hi = min(max(ss_t, 1), max(td - 1, 0));
    int c_hi = min(max(ss_c, 1), max(cd - 1, 0));
    int t_lo = max(t_hi - 1, 0);
    int c_lo = max(c_hi - 1, 0);

    float t0 = sel8(ta, tb, t_lo), t1 = sel8(ta, tb, t_hi);
    float c0 = sel8(ca, cb, c_lo), c1 = sel8(ca, cb, c_hi);

    float ti = t1 - t0, ci = c1 - c0;
    float xt = fminf(fmaxf(x_t, t0), t1);
    float xc = fminf(fmaxf(x_c, c0), c1);
    float ti_s = (fabsf(ti) < EPS) ? EPS : ti;
    float ci_s = (fabsf(ci) < EPS) ? EPS : ci;
    float ft = fminf(fmaxf((xt - t0) / ti_s, 0.f), 1.f);
    float fc = fminf(fmaxf((xc - c0) / ci_s, 0.f), 1.f);

    bool is2d = (td > 1) && (cd > 1);
    bool is1t = (td > 1) && (cd <= 1);
    bool is1c = (td <= 1) && (cd > 1);

    // Pair bases: in every mode the needed values are two adjacent pairs.
    //  2D: (i00,i00+1),(i10,i10+1); 1t: (t_lo),(t_hi); 1c: (c_lo,c_lo+1); scalar: (0)
    int iA = is2d ? (t_lo * cd + c_lo) : is1t ? t_lo : is1c ? c_lo : 0;
    int iB = is2d ? (t_hi * cd + c_lo) : is1t ? t_hi : iA;
    int dA = (is2d || is1c) ? 1 : 0;   // v01 = vals[iA + dA]
    int dB = is2d ? 1 : 0;             // v11 = vals[iB + dB]

    const float* vrow = values + (size_t)arc * 64;
    // 16B-aligned quads containing iA / iB (always within the 64-float row)
    int bA = iA & ~3, oA = iA & 3;
    int bB = iB & ~3, oB = iB & 3;
    vf4 qA = *(const vf4*)(vrow + bA);
    vf4 qB = *(const vf4*)(vrow + bB);
    float v00 = sel4(qA, oA);
    float v10 = sel4(qB, oB);
    // fixup loads only when the pair straddles the aligned quad (exec-masked, ~19%)
    float v01 = (oA + dA <= 3) ? sel4(qA, oA + dA) : vrow[iA + dA];
    float v11 = (oB + dB <= 3) ? sel4(qB, oB + dB) : vrow[iB + dB];

    float wa = (t1 - xt) * (c1 - xc);
    float wb = (t1 - xt) * (xc - c0);
    float wc = (xt - t0) * (c1 - xc);
    float wd = (xt - t0) * (xc - c0);
    float bil = (v00 * wa + v01 * wb + v10 * wc + v11 * wd) / (ti_s * ci_s);

    float lin_t = v00 + (v10 - v00) * ft;
    float lin_c = v00 + (v01 - v00) * fc;

    float r = is2d ? bil : is1t ? lin_t : is1c ? lin_c : v00;
    __builtin_nontemporal_store(r, out + i);
}

extern "C" void kernel_launch(void* const* d_in, const int* in_sizes, int n_in,
                              void* d_out, int out_size, void* d_ws, size_t ws_size,
                              hipStream_t stream) {
    const float* x_t   = (const float*)d_in[0];
    const float* x_c   = (const float*)d_in[1];
    const int*   arcs  = (const int*)d_in[2];
    const float* vals  = (const float*)d_in[3];
    const float* t_tbl = (const float*)d_in[4];
    const float* c_tbl = (const float*)d_in[5];
    const int*   dims  = (const int*)d_in[6];
    float* out = (float*)d_out;
    int B = in_sizes[0];

    (void)d_ws; (void)ws_size;  // deliberately unused: testing ws-poison conditionality

    int gridB = (B + 255) / 256;
    TimingPropagation_35622458753425_kernel<<<gridB, 256, 0, stream>>>(
        x_t, x_c, arcs, vals, t_tbl, c_tbl, dims, out, B);
}

// Round 2
// 269.083 us; speedup vs baseline: 1.0846x; 1.0846x over previous
//
#include <hip/hip_runtime.h>

#define EPS 1e-12f

typedef float vf4 __attribute__((ext_vector_type(4)));
typedef float vf2 __attribute__((ext_vector_type(2)));
typedef int   vi2 __attribute__((ext_vector_type(2)));

__device__ __forceinline__ float sel8(const vf4& a, const vf4& b, int i) {
    float lo = (i == 0) ? a.x : (i == 1) ? a.y : (i == 2) ? a.z : a.w;
    float hi = (i == 4) ? b.x : (i == 5) ? b.y : (i == 6) ? b.z : b.w;
    return (i < 4) ? lo : hi;
}

__device__ __forceinline__ float sel4(const vf4& q, int i) {
    return (i == 0) ? q.x : (i == 1) ? q.y : (i == 2) ? q.z : q.w;
}

// ---- repack: interleave t_tbl|c_tbl into one 64B record/arc; dims -> nibble-packed byte ----
__global__ __launch_bounds__(256) void k_repack(const float* __restrict__ t_table,
                                                const float* __restrict__ c_table,
                                                const int* __restrict__ dims,
                                                vf4* __restrict__ packed,          // [N*4]
                                                unsigned char* __restrict__ dims8, // [N]
                                                int N) {
    int a = blockIdx.x * blockDim.x + threadIdx.x;
    if (a >= N) return;
    const vf4* tt = (const vf4*)(t_table + (size_t)a * 8);
    const vf4* cc = (const vf4*)(c_table + (size_t)a * 8);
    vf4 t0 = __builtin_nontemporal_load(tt);
    vf4 t1 = __builtin_nontemporal_load(tt + 1);
    vf4 c0 = __builtin_nontemporal_load(cc);
    vf4 c1 = __builtin_nontemporal_load(cc + 1);
    vf4* dst = packed + (size_t)a * 4;
    // regular stores (not NT): main kernel gathers these immediately -> keep in cache
    dst[0] = t0;
    dst[1] = t1;
    dst[2] = c0;
    dst[3] = c1;
    vi2 d = __builtin_nontemporal_load((const vi2*)dims + a);
    dims8[a] = (unsigned char)((d.x & 0xF) | ((d.y & 0xF) << 4));
}

// ---- main kernel: 2 evals/thread -> two independent gather chains in flight ----
// Chain per eval: arc -> dims8 (0.5MB, cache-resident) -> 64B packed record -> value quads.
// Stages are unrolled loops over k=0..1 so both chains' loads issue back-to-back.
__global__ __launch_bounds__(256) void k_main_d8x2(
    const float* __restrict__ x_t_arr, const float* __restrict__ x_c_arr,
    const int* __restrict__ arcs, const float* __restrict__ values,
    const vf4* __restrict__ packed, const unsigned char* __restrict__ dims8,
    float* __restrict__ out, int B)
{
    int i = blockIdx.x * blockDim.x + threadIdx.x;
    int j = i * 2;
    if (j >= B) return;
    bool two = (j + 1 < B);

    float xt_[2], xc_[2];
    int arc_[2];
    if (two) {
        vf2 t2 = __builtin_nontemporal_load((const vf2*)x_t_arr + i);
        vf2 c2 = __builtin_nontemporal_load((const vf2*)x_c_arr + i);
        vi2 a2 = __builtin_nontemporal_load((const vi2*)arcs + i);
        xt_[0] = t2.x; xt_[1] = t2.y;
        xc_[0] = c2.x; xc_[1] = c2.y;
        arc_[0] = a2.x; arc_[1] = a2.y;
    } else {
        float xt = x_t_arr[j], xc = x_c_arr[j]; int a = arcs[j];
        xt_[0] = xt_[1] = xt; xc_[0] = xc_[1] = xc; arc_[0] = arc_[1] = a;
    }

    // stage 1: both dims-nibble gathers in flight
    unsigned char dp_[2];
#pragma unroll
    for (int k = 0; k < 2; ++k) dp_[k] = dims8[arc_[k]];

    int td_[2], cd_[2];
    bool valid_[2];
#pragma unroll
    for (int k = 0; k < 2; ++k) {
        td_[k] = dp_[k] & 0xF;
        cd_[k] = dp_[k] >> 4;
        valid_[k] = (td_[k] != 0) && (cd_[k] != 0);
    }

    // stage 2: both 64B record gathers in flight (exec-masked off for invalid ~21%)
    vf4 z = {0.f, 0.f, 0.f, 0.f};
    vf4 ta_[2] = {z, z}, tb_[2] = {z, z}, ca_[2] = {z, z}, cb_[2] = {z, z};
#pragma unroll
    for (int k = 0; k < 2; ++k) {
        if (valid_[k]) {
            const vf4* rec = packed + (size_t)arc_[k] * 4;
            ta_[k] = rec[0]; tb_[k] = rec[1]; ca_[k] = rec[2]; cb_[k] = rec[3];
        }
    }

    // stage 3: searchsorted + interpolation setup (pure VALU, overlaps stage-2 latency)
    int iA_[2], iB_[2], dA_[2], dB_[2], bA_[2], oA_[2], bB_[2], oB_[2];
    float wa_[2], wb_[2], wc_[2], wd_[2], ft_[2], fc_[2], den_[2];
    bool is2d_[2], is1t_[2], is1c_[2];
#pragma unroll
    for (int k = 0; k < 2; ++k) {
        float x_t = xt_[k], x_c = xc_[k];
        vf4 ta = ta_[k], tb = tb_[k], ca = ca_[k], cb = cb_[k];
        int td = td_[k], cd = cd_[k];

        int ss_t = (ta.x <= x_t) + (ta.y <= x_t) + (ta.z <= x_t) + (ta.w <= x_t)
                 + (tb.x <= x_t) + (tb.y <= x_t) + (tb.z <= x_t) + (tb.w <= x_t);
        int ss_c = (ca.x <= x_c) + (ca.y <= x_c) + (ca.z <= x_c) + (ca.w <= x_c)
                 + (cb.x <= x_c) + (cb.y <= x_c) + (cb.z <= x_c) + (cb.w <= x_c);

        int t_hi = min(max(ss_t, 1), max(td - 1, 0));
        int c_hi = min(max(ss_c, 1), max(cd - 1, 0));
        int t_lo = max(t_hi - 1, 0);
        int c_lo = max(c_hi - 1, 0);

        float t0 = sel8(ta, tb, t_lo), t1 = sel8(ta, tb, t_hi);
        float c0 = sel8(ca, cb, c_lo), c1 = sel8(ca, cb, c_hi);

        float ti = t1 - t0, ci = c1 - c0;
        float xt = fminf(fmaxf(x_t, t0), t1);
        float xc = fminf(fmaxf(x_c, c0), c1);
        float ti_s = (fabsf(ti) < EPS) ? EPS : ti;
        float ci_s = (fabsf(ci) < EPS) ? EPS : ci;
        ft_[k] = fminf(fmaxf((xt - t0) / ti_s, 0.f), 1.f);
        fc_[k] = fminf(fmaxf((xc - c0) / ci_s, 0.f), 1.f);

        bool is2d = (td > 1) && (cd > 1);
        bool is1t = (td > 1) && (cd <= 1);
        bool is1c = (td <= 1) && (cd > 1);

        // Pair bases: in every mode the needed values are two adjacent pairs.
        int iA = is2d ? (t_lo * cd + c_lo) : is1t ? t_lo : is1c ? c_lo : 0;
        int iB = is2d ? (t_hi * cd + c_lo) : is1t ? t_hi : iA;
        iA_[k] = iA; iB_[k] = iB;
        dA_[k] = (is2d || is1c) ? 1 : 0;
        dB_[k] = is2d ? 1 : 0;
        bA_[k] = iA & ~3; oA_[k] = iA & 3;
        bB_[k] = iB & ~3; oB_[k] = iB & 3;

        wa_[k] = (t1 - xt) * (c1 - xc);
        wb_[k] = (t1 - xt) * (xc - c0);
        wc_[k] = (xt - t0) * (c1 - xc);
        wd_[k] = (xt - t0) * (xc - c0);
        den_[k] = ti_s * ci_s;
        is2d_[k] = is2d; is1t_[k] = is1t; is1c_[k] = is1c;
    }

    // stage 4: both value-quad gather pairs in flight (+ rare straddle fixups)
    vf4 qA_[2] = {z, z}, qB_[2] = {z, z};
    float v01f_[2] = {0.f, 0.f}, v11f_[2] = {0.f, 0.f};
#pragma unroll
    for (int k = 0; k < 2; ++k) {
        if (valid_[k]) {
            const float* vrow = values + (size_t)arc_[k] * 64;
            qA_[k] = *(const vf4*)(vrow + bA_[k]);
            qB_[k] = *(const vf4*)(vrow + bB_[k]);
            if (oA_[k] + dA_[k] > 3) v01f_[k] = vrow[iA_[k] + dA_[k]];
            if (oB_[k] + dB_[k] > 3) v11f_[k] = vrow[iB_[k] + dB_[k]];
        }
    }

    // stage 5: combine
    float r_[2];
#pragma unroll
    for (int k = 0; k < 2; ++k) {
        float v00 = sel4(qA_[k], oA_[k]);
        float v10 = sel4(qB_[k], oB_[k]);
        float v01 = (oA_[k] + dA_[k] <= 3) ? sel4(qA_[k], oA_[k] + dA_[k]) : v01f_[k];
        float v11 = (oB_[k] + dB_[k] <= 3) ? sel4(qB_[k], oB_[k] + dB_[k]) : v11f_[k];

        float bil = (v00 * wa_[k] + v01 * wb_[k] + v10 * wc_[k] + v11 * wd_[k]) / den_[k];
        float lin_t = v00 + (v10 - v00) * ft_[k];
        float lin_c = v00 + (v01 - v00) * fc_[k];

        float r = is2d_[k] ? bil : is1t_[k] ? lin_t : is1c_[k] ? lin_c : v00;
        r_[k] = valid_[k] ? r : 0.0f;
    }

    if (two) {
        vf2 o2; o2.x = r_[0]; o2.y = r_[1];
        __builtin_nontemporal_store(o2, (vf2*)out + i);
    } else {
        __builtin_nontemporal_store(r_[0], out + j);
    }
}

// ---- fallback: fully direct (if ws too small) ----
__global__ __launch_bounds__(256) void TimingPropagation_35622458753425_kernel(
    const float* __restrict__ x_t_arr, const float* __restrict__ x_c_arr,
    const int* __restrict__ arcs, const float* __restrict__ values,
    const float* __restrict__ t_table, const float* __restrict__ c_table,
    const int* __restrict__ dims, float* __restrict__ out, int B)
{
    int i = blockIdx.x * blockDim.x + threadIdx.x;
    if (i >= B) return;
    int arc = arcs[i];
    int td = dims[2 * arc], cd = dims[2 * arc + 1];
    if (td == 0 || cd == 0) { out[i] = 0.0f; return; }
    float x_t = x_t_arr[i], x_c = x_c_arr[i];
    const vf4* tt = (const vf4*)(t_table + (size_t)arc * 8);
    const vf4* cc = (const vf4*)(c_table + (size_t)arc * 8);
    vf4 ta = tt[0], tb = tt[1], ca = cc[0], cb = cc[1];
    int ss_t = (ta.x <= x_t) + (ta.y <= x_t) + (ta.z <= x_t) + (ta.w <= x_t)
             + (tb.x <= x_t) + (tb.y <= x_t) + (tb.z <= x_t) + (tb.w <= x_t);
    int ss_c = (ca.x <= x_c) + (ca.y <= x_c) + (ca.z <= x_c) + (ca.w <= x_c)
             + (cb.x <= x_c) + (cb.y <= x_c) + (cb.z <= x_c) + (cb.w <= x_c);
    int t_hi = min(max(ss_t, 1), max(td - 1, 0));
    int c_hi = min(max(ss_c, 1), max(cd - 1, 0));
    int t_lo = max(t_hi - 1, 0);
    int c_lo = max(c_hi - 1, 0);
    float t0 = sel8(ta, tb, t_lo), t1 = sel8(ta, tb, t_hi);
    float c0 = sel8(ca, cb, c_lo), c1 = sel8(ca, cb, c_hi);
    float ti = t1 - t0, ci = c1 - c0;
    float xt = fminf(fmaxf(x_t, t0), t1);
    float xc = fminf(fmaxf(x_c, c0), c1);
    float ti_s = (fabsf(ti) < EPS) ? EPS : ti;
    float ci_s = (fabsf(ci) < EPS) ? EPS : ci;
    float ft = fminf(fmaxf((xt - t0) / ti_s, 0.f), 1.f);
    float fc = fminf(fmaxf((xc - c0) / ci_s, 0.f), 1.f);
    bool is2d = (td > 1) && (cd > 1);
    bool is1t = (td > 1) && (cd <= 1);
    bool is1c = (td <= 1) && (cd > 1);
    int i00 = is2d ? (t_lo * cd + c_lo) : is1t ? t_lo : is1c ? c_lo : 0;
    int i01 = is2d ? (t_lo * cd + c_hi) : is1c ? c_hi : i00;
    int i10 = is2d ? (t_hi * cd + c_lo) : is1t ? t_hi : i00;
    int i11 = is2d ? (t_hi * cd + c_hi) : i00;
    const float* vrow = values + (size_t)arc * 64;
    float v00 = vrow[i00], v01 = vrow[i01], v10 = vrow[i10], v11 = vrow[i11];
    float wa = (t1 - xt) * (c1 - xc);
    float wb = (t1 - xt) * (xc - c0);
    float wc = (xt - t0) * (c1 - xc);
    float wd = (xt - t0) * (xc - c0);
    float bil = (v00 * wa + v01 * wb + v10 * wc + v11 * wd) / (ti_s * ci_s);
    float lin_t = v00 + (v10 - v00) * ft;
    float lin_c = v00 + (v01 - v00) * fc;
    out[i] = is2d ? bil : is1t ? lin_t : is1c ? lin_c : v00;
}

extern "C" void kernel_launch(void* const* d_in, const int* in_sizes, int n_in,
                              void* d_out, int out_size, void* d_ws, size_t ws_size,
                              hipStream_t stream) {
    const float* x_t   = (const float*)d_in[0];
    const float* x_c   = (const float*)d_in[1];
    const int*   arcs  = (const int*)d_in[2];
    const float* vals  = (const float*)d_in[3];
    const float* t_tbl = (const float*)d_in[4];
    const float* c_tbl = (const float*)d_in[5];
    const int*   dims  = (const int*)d_in[6];
    float* out = (float*)d_out;
    int B = in_sizes[0];
    int N = in_sizes[3] / 64;

    size_t need_tc = (size_t)N * 64;        // packed t|c records
    size_t need_d8 = need_tc + (size_t)N;   // + nibble dims

    int gridN = (N + 255) / 256;
    int halfB = (B + 1) / 2;
    int gridB2 = (halfB + 255) / 256;
    int gridB = (B + 255) / 256;

    if (ws_size >= need_d8) {
        vf4* packed = (vf4*)d_ws;
        unsigned char* dims8 = (unsigned char*)d_ws + need_tc;
        k_repack<<<gridN, 256, 0, stream>>>(t_tbl, c_tbl, dims, packed, dims8, N);
        k_main_d8x2<<<gridB2, 256, 0, stream>>>(x_t, x_c, arcs, vals, packed, dims8, out, B);
    } else {
        TimingPropagation_35622458753425_kernel<<<gridB, 256, 0, stream>>>(
            x_t, x_c, arcs, vals, t_tbl, c_tbl, dims, out, B);
    }
}